// Round 14
// baseline (359.863 us; speedup 1.0000x reference)
//
#include <hip/hip_runtime.h>
#include <hip/hip_bf16.h>
#include <math.h>

#define N_NODES 4096
#define FDIM 512            // K of both GEMMs (F_in = H*D = 512)
#define D 64
#define H 8
#define NWORDS (N_NODES / 64)

typedef __attribute__((ext_vector_type(8))) short bf16x8;   // 8 bf16 = 4 VGPRs
typedef __attribute__((ext_vector_type(4))) float f32x4;

__device__ inline short f2bf(float x) {                     // RNE
    return (short)((__builtin_bit_cast(unsigned int, x) + 0x8000u) >> 16);
}
__device__ inline float b2f(unsigned short s) {
    return __builtin_bit_cast(float, (unsigned int)s << 16);
}

__device__ inline int sext_bit(unsigned int v, int j) {     // all-ones iff bit j set
#if defined(__has_builtin) && __has_builtin(__builtin_amdgcn_sbfe)
    return __builtin_amdgcn_sbfe((int)v, j, 1);
#else
    return ((int)(v << (31 - j))) >> 31;
#endif
}

// monotonic float<->uint encoding so unsigned atomicMax == float max
__device__ inline unsigned fenc(float f) {
    unsigned u = __builtin_bit_cast(unsigned, f);
    return (u & 0x80000000u) ? ~u : (u | 0x80000000u);
}
__device__ inline float fdec(unsigned e) {
    unsigned u = (e & 0x80000000u) ? (e & 0x7FFFFFFFu) : ~e;
    return __builtin_bit_cast(float, u);
}

// ---------------------------------------------------------------- fused preprocessing
// band 0: zero cm/gmax; bands: adj->bits (8/thread, int4 loads) | X->bf16 (4/thread) | W | W_o
#define NB_BITS (N_NODES * N_NODES / 2048)     // 8 adj per thread
#define NB_X    (N_NODES * FDIM / 1024)        // 4 floats per thread
#define NB_W    (H * FDIM * D / 256)
#define NB_WO   (FDIM * D / 256)
__global__ void k_pre(const int* __restrict__ adj, const float* __restrict__ x,
                      const float* __restrict__ W, const float* __restrict__ Wo,
                      unsigned int* __restrict__ bits32, short* __restrict__ Xbf,
                      short* __restrict__ WF, short* __restrict__ WoF,
                      float* __restrict__ cm1, float* __restrict__ cm2,
                      unsigned* __restrict__ gmaxe1, unsigned* __restrict__ gmaxe2) {
    const int b = blockIdx.x, t = threadIdx.x;
    if (b == 0) {
        for (int i = t; i < H * D; i += 256) cm1[i] = 0.f;
        if (t < D) cm2[t] = 0.f;
        if (t < H) gmaxe1[t] = 0u;
        if (t == 0) gmaxe2[0] = 0u;
        return;
    }
    if (b < 1 + NB_BITS) {
        const int tid  = (b - 1) * 256 + t;     // one byte (8 adj) per thread
        const size_t e0 = (size_t)tid * 8;
        int4 a0 = *(const int4*)&adj[e0];
        int4 a1 = *(const int4*)&adj[e0 + 4];
        unsigned by = (unsigned)(a0.x != 0)       | ((unsigned)(a0.y != 0) << 1)
                    | ((unsigned)(a0.z != 0) << 2) | ((unsigned)(a0.w != 0) << 3)
                    | ((unsigned)(a1.x != 0) << 4) | ((unsigned)(a1.y != 0) << 5)
                    | ((unsigned)(a1.z != 0) << 6) | ((unsigned)(a1.w != 0) << 7);
        unsigned v = by | (__shfl_xor((int)by, 1) << 8);
        v = v | ((unsigned)__shfl_xor((int)v, 2) << 16);
        if ((t & 3) == 0) bits32[tid >> 2] = v;
        return;
    }
    if (b < 1 + NB_BITS + NB_X) {
        const size_t i4 = ((size_t)(b - 1 - NB_BITS) * 256 + t) * 4;
        float4 v = *(const float4*)&x[i4];
        ushort4 o;
        o.x = (unsigned short)f2bf(v.x); o.y = (unsigned short)f2bf(v.y);
        o.z = (unsigned short)f2bf(v.z); o.w = (unsigned short)f2bf(v.w);
        *(ushort4*)&Xbf[i4] = o;
        return;
    }
    if (b < 1 + NB_BITS + NB_X + NB_W) {
        const size_t idx = (size_t)(b - 1 - NB_BITS - NB_X) * 256 + t;   // (h*512+k)*64+d
        const int d = idx & 63;
        const int k = (int)(idx >> 6) & 511;
        const int h = (int)(idx >> 15);
        WF[(((size_t)h * 64 + (k >> 3)) * 64 + d) * 8 + (k & 7)] = f2bf(W[idx]);
        return;
    }
    {
        const size_t idx = (size_t)(b - 1 - NB_BITS - NB_X - NB_W) * 256 + t;  // k*64+d
        const int d = idx & 63;
        const int k = (int)(idx >> 6);
        WoF[(((size_t)(k >> 3)) * 64 + d) * 8 + (k & 7)] = f2bf(Wo[idx]);
    }
}

// ---------------------------------------------------------------- MFMA GEMM [N,512]@[512,64] per head
// bf16 A from global; writes bf16 frag copy of C, fused fs/fd row dot-products,
// and fused per-head stats: gmax(fd) via encoded atomicMax, colmean via atomicAdd.
__global__ void __launch_bounds__(256) k_gemm(
    const short* __restrict__ Xbf, const short* __restrict__ WF,
    const float* __restrict__ av, const float* __restrict__ bv,
    short* __restrict__ WBout, float* __restrict__ fs, float* __restrict__ fd,
    unsigned* __restrict__ gmaxe, float* __restrict__ cm) {
    const int h  = blockIdx.y;
    const int i0 = blockIdx.x * 64;
    const int t = threadIdx.x, w = t >> 6, lane = t & 63;
    const int li = lane & 15, quad = lane >> 4, k0 = quad * 8;
    const int row_a = i0 + w * 16 + li;
    const short* __restrict__ Xr  = Xbf + (size_t)row_a * FDIM;
    const short* __restrict__ WFh = WF + (size_t)h * 64 * D * 8;

    f32x4 c0 = {0.f, 0.f, 0.f, 0.f}, c1 = c0, c2 = c0, c3 = c0;
    #pragma unroll 4
    for (int kt = 0; kt < FDIM; kt += 32) {
        bf16x8 a = *(const bf16x8*)&Xr[kt + k0];
        const short* bb = WFh + (size_t)((kt >> 3) + quad) * (D * 8) + li * 8;
        bf16x8 b0 = *(const bf16x8*)(bb);
        bf16x8 b1 = *(const bf16x8*)(bb + 128);
        bf16x8 b2 = *(const bf16x8*)(bb + 256);
        bf16x8 b3 = *(const bf16x8*)(bb + 384);
        c0 = __builtin_amdgcn_mfma_f32_16x16x32_bf16(a, b0, c0, 0, 0, 0);
        c1 = __builtin_amdgcn_mfma_f32_16x16x32_bf16(a, b1, c1, 0, 0, 0);
        c2 = __builtin_amdgcn_mfma_f32_16x16x32_bf16(a, b2, c2, 0, 0, 0);
        c3 = __builtin_amdgcn_mfma_f32_16x16x32_bf16(a, b3, c3, 0, 0, 0);
    }
    float av4[4], bv4[4];
    #pragma unroll
    for (int t4 = 0; t4 < 4; ++t4) {
        av4[t4] = av[h * D + t4 * 16 + li];
        bv4[t4] = bv[h * D + t4 * 16 + li];
    }
    float tiles[4][4];
    #pragma unroll
    for (int r = 0; r < 4; ++r) { tiles[0][r] = c0[r]; tiles[1][r] = c1[r]; tiles[2][r] = c2[r]; tiles[3][r] = c3[r]; }

    __shared__ float csum[4][64];
    __shared__ float red[4];
    float fdmax = -INFINITY;
    float s4[4] = {0.f, 0.f, 0.f, 0.f};

    #pragma unroll
    for (int r = 0; r < 4; ++r) {
        const int row = i0 + w * 16 + quad * 4 + r;
        float pa = 0.f, pb = 0.f;
        #pragma unroll
        for (int t4 = 0; t4 < 4; ++t4) {
            const float v = tiles[t4][r];
            const int d = t4 * 16 + li;
            WBout[((size_t)h * (N_NODES / 8) + (row >> 3)) * (D * 8) + d * 8 + (row & 7)] = f2bf(v);
            pa += v * av4[t4];
            pb += v * bv4[t4];
            s4[t4] += v;
        }
        #pragma unroll
        for (int off = 1; off < 16; off <<= 1) {
            pa += __shfl_xor(pa, off);
            pb += __shfl_xor(pb, off);
        }
        if (li == 0) {
            fs[(size_t)h * N_NODES + row] = pa;
            fd[(size_t)h * N_NODES + row] = pb;
        }
        fdmax = fmaxf(fdmax, pb);
    }
    fdmax = fmaxf(fdmax, __shfl_xor(fdmax, 16));
    fdmax = fmaxf(fdmax, __shfl_xor(fdmax, 32));
    if (lane == 0) red[w] = fdmax;
    #pragma unroll
    for (int t4 = 0; t4 < 4; ++t4) {
        s4[t4] += __shfl_xor(s4[t4], 16);
        s4[t4] += __shfl_xor(s4[t4], 32);
    }
    if (quad == 0)
        #pragma unroll
        for (int t4 = 0; t4 < 4; ++t4) csum[w][t4 * 16 + li] = s4[t4];
    __syncthreads();
    if (t == 0)
        atomicMax(gmaxe + h, fenc(fmaxf(fmaxf(red[0], red[1]), fmaxf(red[2], red[3]))));
    if (t < 64)
        atomicAdd(&cm[h * D + t],
                  (csum[0][t] + csum[1][t] + csum[2][t] + csum[3][t]) * (1.f / (float)N_NODES));
}

// ---------------------------------------------------------------- MFMA attention aggregation (j-split)
// BARRIER-FREE: 64 rows/wave, 4 A-frags; B-fragments streamed directly from
// global (L2/L3-resident); e/g staged in wave-private LDS (within-wave
// ds ordering needs only lgkmcnt, no __syncthreads). Every wave runs
// independently — no per-tile rendezvous drain.
__global__ void __launch_bounds__(256, 4) k_accum(
    const unsigned int* __restrict__ bits32,
    const short* __restrict__ WB,
    const float* __restrict__ fsb, const float* __restrict__ fdb,
    const unsigned* __restrict__ gmaxe,
    short* __restrict__ num, float* __restrict__ den, int kslab) {

    __shared__ __align__(16) float EG[4][256];   // per-wave: e[0..127], g[128..255]

    const int h = blockIdx.y, i0 = blockIdx.x * 256, slab = blockIdx.z;
    const int t = threadIdx.x, w = t >> 6, lane = t & 63;
    const int li = lane & 15, quad = lane >> 4, k0 = quad * 8;
    const size_t ho = (size_t)h * N_NODES;
    const float  gm = fdec(gmaxe[h]);
    float Rv[4];
    const unsigned int* __restrict__ brow[4];
    #pragma unroll
    for (int f = 0; f < 4; ++f) {
        const int r = i0 + w * 64 + f * 16 + li;
        Rv[f] = __expf(-0.8f * (fsb[ho + r] + gm));
        brow[f] = bits32 + (size_t)r * (NWORDS * 2);
    }
    const float* __restrict__ fd = fdb + ho;
    const short* __restrict__ Bh = WB + (size_t)h * (N_NODES / 8) * D * 8;
    float* __restrict__ EGw = EG[w];

    f32x4 acc[4][4], c5[4];
    #pragma unroll
    for (int f = 0; f < 4; ++f) {
        #pragma unroll
        for (int q = 0; q < 4; ++q) acc[f][q] = (f32x4){0.f, 0.f, 0.f, 0.f};
        c5[f] = (f32x4){0.f, 0.f, 0.f, 0.f};
    }
    bf16x8 ones;
    #pragma unroll
    for (int j = 0; j < 8; ++j) ones[j] = (short)0x3F80;

    const int k_beg = slab * kslab, k_end = k_beg + kslab;

    for (int jt = k_beg; jt < k_end; jt += 128) {
        // wave-private e/g for this 128-j tile (no block barrier needed)
        {
            float2 f2 = *(const float2*)&fd[jt + lane * 2];
            float2 ev, gv;
            ev.x = __expf(f2.x - gm);          ev.y = __expf(f2.y - gm);
            gv.x = __expf(0.2f * (f2.x - gm)); gv.y = __expf(0.2f * (f2.y - gm));
            *(float2*)&EGw[lane * 2]       = ev;
            *(float2*)&EGw[128 + lane * 2] = gv;
        }
        uint4 bw[4];
        #pragma unroll
        for (int f = 0; f < 4; ++f) bw[f] = *(const uint4*)&brow[f][jt >> 5];
        unsigned int bwa[4][4];
        #pragma unroll
        for (int f = 0; f < 4; ++f) {
            bwa[f][0] = bw[f].x; bwa[f][1] = bw[f].y; bwa[f][2] = bw[f].z; bwa[f][3] = bw[f].w;
        }
        #pragma unroll
        for (int s = 0; s < 4; ++s) {
            const float4 e0 = *(const float4*)&EGw[s * 32 + k0];
            const float4 e1 = *(const float4*)&EGw[s * 32 + k0 + 4];
            const float4 g0 = *(const float4*)&EGw[128 + s * 32 + k0];
            const float4 g1 = *(const float4*)&EGw[128 + s * 32 + k0 + 4];
            float ev[8], gv[8];
            ev[0] = e0.x; ev[1] = e0.y; ev[2] = e0.z; ev[3] = e0.w;
            ev[4] = e1.x; ev[5] = e1.y; ev[6] = e1.z; ev[7] = e1.w;
            gv[0] = g0.x; gv[1] = g0.y; gv[2] = g0.z; gv[3] = g0.w;
            gv[4] = g1.x; gv[5] = g1.y; gv[6] = g1.z; gv[7] = g1.w;
            // B-fragments straight from global (L2/L3-resident, 4 x 256B segments)
            const short* bb = Bh + (size_t)(((jt + s * 32) >> 3) + quad) * (D * 8) + li * 8;
            bf16x8 b0 = *(const bf16x8*)(bb);
            bf16x8 b1 = *(const bf16x8*)(bb + 128);
            bf16x8 b2 = *(const bf16x8*)(bb + 256);
            bf16x8 b3 = *(const bf16x8*)(bb + 384);
            #pragma unroll
            for (int f = 0; f < 4; ++f) {
                const unsigned int byt = (bwa[f][s] >> k0) & 0xFFu;
                unsigned int pa[8];
                #pragma unroll
                for (int j = 0; j < 8; ++j) {
                    const float p = fmaxf(ev[j], gv[j] * Rv[f]);   // == leaky branch select
                    pa[j] = __builtin_bit_cast(unsigned int, p)
                            & (unsigned int)sext_bit(byt, j);
                }
                bf16x8 a;
                unsigned int* au = (unsigned int*)&a;
                au[0] = __builtin_amdgcn_perm(pa[1], pa[0], 0x07060302);
                au[1] = __builtin_amdgcn_perm(pa[3], pa[2], 0x07060302);
                au[2] = __builtin_amdgcn_perm(pa[5], pa[4], 0x07060302);
                au[3] = __builtin_amdgcn_perm(pa[7], pa[6], 0x07060302);
                acc[f][0] = __builtin_amdgcn_mfma_f32_16x16x32_bf16(a, b0, acc[f][0], 0, 0, 0);
                acc[f][1] = __builtin_amdgcn_mfma_f32_16x16x32_bf16(a, b1, acc[f][1], 0, 0, 0);
                acc[f][2] = __builtin_amdgcn_mfma_f32_16x16x32_bf16(a, b2, acc[f][2], 0, 0, 0);
                acc[f][3] = __builtin_amdgcn_mfma_f32_16x16x32_bf16(a, b3, acc[f][3], 0, 0, 0);
                c5[f]     = __builtin_amdgcn_mfma_f32_16x16x32_bf16(a, ones, c5[f], 0, 0, 0);
            }
        }
    }

    const size_t so = (size_t)(slab * gridDim.y + h);
    #pragma unroll
    for (int f = 0; f < 4; ++f) {
        #pragma unroll
        for (int t4 = 0; t4 < 4; ++t4)
            #pragma unroll
            for (int r = 0; r < 4; ++r) {
                const int row = i0 + w * 64 + f * 16 + quad * 4 + r;
                num[(so * N_NODES + row) * D + t4 * 16 + li] = f2bf(acc[f][t4][r]);
            }
        if (li == 0)
            #pragma unroll
            for (int r = 0; r < 4; ++r)
                den[so * N_NODES + i0 + w * 64 + f * 16 + quad * 4 + r] = c5[f][r];
    }
}

// ---------------------------------------------------------------- layer-1 combine (JS=8): norm+fallback+ELU, bf16 out
__global__ void k_post1(const short* __restrict__ num, const float* __restrict__ den,
                        const float* __restrict__ colmean, short* __restrict__ hcat) {
    const int h   = blockIdx.y;
    const int i0  = blockIdx.x * 64;
    const int t   = threadIdx.x;
    const int row = i0 + (t >> 2);
    const int cb  = (t & 3) * 16;
    const size_t HN = (size_t)gridDim.y * N_NODES;
    const size_t r0 = (size_t)h * N_NODES + row;
    float dsum = 0.f;
    #pragma unroll
    for (int s = 0; s < 8; ++s) dsum += den[s * HN + r0];
    const bool  uni  = !(dsum > 0.f);
    const float linv = uni ? 0.f : 1.f / dsum;
    #pragma unroll
    for (int c = 0; c < 4; ++c) {
        const int col = cb + c * 4;
        float4 v = {0.f, 0.f, 0.f, 0.f};
        #pragma unroll
        for (int s = 0; s < 8; ++s) {
            ushort4 a = *(const ushort4*)&num[(s * HN + r0) * D + col];
            v.x += b2f(a.x); v.y += b2f(a.y); v.z += b2f(a.z); v.w += b2f(a.w);
        }
        v.x *= linv; v.y *= linv; v.z *= linv; v.w *= linv;
        if (uni) v = *(const float4*)&colmean[h * D + col];
        v.x = v.x > 0.f ? v.x : __expf(v.x) - 1.f;
        v.y = v.y > 0.f ? v.y : __expf(v.y) - 1.f;
        v.z = v.z > 0.f ? v.z : __expf(v.z) - 1.f;
        v.w = v.w > 0.f ? v.w : __expf(v.w) - 1.f;
        ushort4 o;
        o.x = (unsigned short)f2bf(v.x); o.y = (unsigned short)f2bf(v.y);
        o.z = (unsigned short)f2bf(v.z); o.w = (unsigned short)f2bf(v.w);
        *(ushort4*)&hcat[(size_t)row * (H * D) + h * D + col] = o;
    }
}

// ---------------------------------------------------------------- layer-2 combine (JS=32) + ELU + log_softmax
__global__ void k_lsm(const short* __restrict__ num, const float* __restrict__ den,
                      const float* __restrict__ cm, float* __restrict__ out) {
    const int n    = blockIdx.x * 4 + (threadIdx.x >> 6);
    const int lane = threadIdx.x & 63;
    float v = 0.f, ds = 0.f;
    #pragma unroll
    for (int s = 0; s < 32; ++s)
        v += b2f((unsigned short)num[((size_t)s * N_NODES + n) * D + lane]);
    #pragma unroll
    for (int s = 0; s < 32; ++s) ds += den[(size_t)s * N_NODES + n];
    v = (ds > 0.f) ? v / ds : cm[lane];
    v = v > 0.f ? v : __expf(v) - 1.f;
    float mx = v;
    #pragma unroll
    for (int off = 32; off > 0; off >>= 1) mx = fmaxf(mx, __shfl_xor(mx, off));
    float ex = __expf(v - mx);
    float sum = ex;
    #pragma unroll
    for (int off = 32; off > 0; off >>= 1) sum += __shfl_xor(sum, off);
    out[(size_t)n * D + lane] = (v - mx) - __logf(sum);
}

// ----------------------------------------------------------------
extern "C" void kernel_launch(void* const* d_in, const int* in_sizes, int n_in,
                              void* d_out, int out_size, void* d_ws, size_t ws_size,
                              hipStream_t stream) {
    const float* x      = (const float*)d_in[0];
    const int*   adj    = (const int*)d_in[1];
    const float* W      = (const float*)d_in[2];
    const float* a_src  = (const float*)d_in[3];
    const float* a_dst  = (const float*)d_in[4];
    const float* W_o    = (const float*)d_in[5];
    const float* ao_src = (const float*)d_in[6];
    const float* ao_dst = (const float*)d_in[7];
    float* out = (float*)d_out;

    char* wsp = (char*)d_ws;
    size_t off = 0;
    auto alloc = [&](size_t bytes) -> void* {
        void* p = wsp + off;
        off += (bytes + 255) & ~(size_t)255;
        return p;
    };
    unsigned* adj_bits = (unsigned*)alloc((size_t)N_NODES * NWORDS * 8);
    short*    Xbf   = (short*)alloc((size_t)N_NODES * FDIM * 2);
    short*    WF1   = (short*)alloc((size_t)H * 64 * D * 8 * 2);
    short*    WoF   = (short*)alloc((size_t)64 * D * 8 * 2);
    short*    WhB   = (short*)alloc((size_t)H * N_NODES * D * 2);
    float*    fs1   = (float*)alloc((size_t)H * N_NODES * 4);
    float*    fd1   = (float*)alloc((size_t)H * N_NODES * 4);
    unsigned* gme1  = (unsigned*)alloc((size_t)H * 4);
    float*    cm1   = (float*)alloc((size_t)H * D * 4);
    short*    num1  = (short*)alloc((size_t)8 * H * N_NODES * D * 2);
    float*    den1  = (float*)alloc((size_t)8 * H * N_NODES * 4);
    short*    hcat  = (short*)alloc((size_t)N_NODES * H * D * 2);
    short*    WhoB  = (short*)alloc((size_t)N_NODES * D * 2);
    float*    fs2   = (float*)alloc((size_t)N_NODES * 4);
    float*    fd2   = (float*)alloc((size_t)N_NODES * 4);
    unsigned* gme2  = (unsigned*)alloc(4);
    float*    cm2   = (float*)alloc((size_t)D * 4);
    short*    num2  = (short*)alloc((size_t)32 * N_NODES * D * 2);
    float*    den2  = (float*)alloc((size_t)32 * N_NODES * 4);

    k_pre  <<<dim3(1 + NB_BITS + NB_X + NB_W + NB_WO), dim3(256), 0, stream>>>(
        adj, x, W, W_o, adj_bits, Xbf, WF1, WoF, cm1, cm2, gme1, gme2);

    // layer 1 (8 heads, concat + ELU)
    k_gemm <<<dim3(N_NODES / 64, H), dim3(256), 0, stream>>>(Xbf, WF1, a_src, a_dst,
                                                             WhB, fs1, fd1, gme1, cm1);
    k_accum<<<dim3(N_NODES / 256, H, 8), dim3(256), 0, stream>>>(adj_bits, WhB, fs1, fd1, gme1,
                                                                 num1, den1, N_NODES / 8);
    k_post1<<<dim3(N_NODES / 64, H), dim3(256), 0, stream>>>(num1, den1, cm1, hcat);

    // layer 2 (single output head)
    k_gemm <<<dim3(N_NODES / 64, 1), dim3(256), 0, stream>>>(hcat, WoF, ao_src, ao_dst,
                                                             WhoB, fs2, fd2, gme2, cm2);
    k_accum<<<dim3(N_NODES / 256, 1, 32), dim3(256), 0, stream>>>(adj_bits, WhoB, fs2, fd2, gme2,
                                                                  num2, den2, N_NODES / 32);
    k_lsm  <<<dim3(N_NODES / 4), dim3(256), 0, stream>>>(num2, den2, cm2, out);
}

// Round 15
// 203.459 us; speedup vs baseline: 1.7687x; 1.7687x over previous
//
#include <hip/hip_runtime.h>
#include <hip/hip_bf16.h>
#include <math.h>

#define N_NODES 4096
#define FDIM 512            // K of both GEMMs (F_in = H*D = 512)
#define D 64
#define H 8
#define NWORDS (N_NODES / 64)

typedef __attribute__((ext_vector_type(8))) short bf16x8;   // 8 bf16 = 4 VGPRs
typedef __attribute__((ext_vector_type(4))) float f32x4;

__device__ inline short f2bf(float x) {                     // RNE
    return (short)((__builtin_bit_cast(unsigned int, x) + 0x8000u) >> 16);
}
__device__ inline float b2f(unsigned short s) {
    return __builtin_bit_cast(float, (unsigned int)s << 16);
}

__device__ inline int sext_bit(unsigned int v, int j) {     // all-ones iff bit j set
#if defined(__has_builtin) && __has_builtin(__builtin_amdgcn_sbfe)
    return __builtin_amdgcn_sbfe((int)v, j, 1);
#else
    return ((int)(v << (31 - j))) >> 31;
#endif
}

// monotonic float<->uint encoding so unsigned atomicMax == float max
__device__ inline unsigned fenc(float f) {
    unsigned u = __builtin_bit_cast(unsigned, f);
    return (u & 0x80000000u) ? ~u : (u | 0x80000000u);
}
__device__ inline float fdec(unsigned e) {
    unsigned u = (e & 0x80000000u) ? (e & 0x7FFFFFFFu) : ~e;
    return __builtin_bit_cast(float, u);
}

// async global->LDS 16B copy (DMA). LDS dst must be wave-uniform base + lane*16.
__device__ inline void gl2lds16(const void* g, void* l) {
#if defined(__has_builtin) && __has_builtin(__builtin_amdgcn_global_load_lds)
    __builtin_amdgcn_global_load_lds(
        (const __attribute__((address_space(1))) unsigned int*)g,
        (__attribute__((address_space(3))) unsigned int*)l, 16, 0, 0);
#else
    *(uint4*)l = *(const uint4*)g;
#endif
}

// ---------------------------------------------------------------- fused preprocessing
// band 0: zero cm/gmax; bands: adj->bits (8/thread, int4 loads) | X->bf16 (4/thread) | W | W_o
#define NB_BITS (N_NODES * N_NODES / 2048)     // 8 adj per thread
#define NB_X    (N_NODES * FDIM / 1024)        // 4 floats per thread
#define NB_W    (H * FDIM * D / 256)
#define NB_WO   (FDIM * D / 256)
__global__ void k_pre(const int* __restrict__ adj, const float* __restrict__ x,
                      const float* __restrict__ W, const float* __restrict__ Wo,
                      unsigned int* __restrict__ bits32, short* __restrict__ Xbf,
                      short* __restrict__ WF, short* __restrict__ WoF,
                      float* __restrict__ cm1, float* __restrict__ cm2,
                      unsigned* __restrict__ gmaxe1, unsigned* __restrict__ gmaxe2) {
    const int b = blockIdx.x, t = threadIdx.x;
    if (b == 0) {
        for (int i = t; i < H * D; i += 256) cm1[i] = 0.f;
        if (t < D) cm2[t] = 0.f;
        if (t < H) gmaxe1[t] = 0u;
        if (t == 0) gmaxe2[0] = 0u;
        return;
    }
    if (b < 1 + NB_BITS) {
        const int tid  = (b - 1) * 256 + t;     // one byte (8 adj) per thread
        const size_t e0 = (size_t)tid * 8;
        int4 a0 = *(const int4*)&adj[e0];
        int4 a1 = *(const int4*)&adj[e0 + 4];
        unsigned by = (unsigned)(a0.x != 0)       | ((unsigned)(a0.y != 0) << 1)
                    | ((unsigned)(a0.z != 0) << 2) | ((unsigned)(a0.w != 0) << 3)
                    | ((unsigned)(a1.x != 0) << 4) | ((unsigned)(a1.y != 0) << 5)
                    | ((unsigned)(a1.z != 0) << 6) | ((unsigned)(a1.w != 0) << 7);
        unsigned v = by | (__shfl_xor((int)by, 1) << 8);
        v = v | ((unsigned)__shfl_xor((int)v, 2) << 16);
        if ((t & 3) == 0) bits32[tid >> 2] = v;
        return;
    }
    if (b < 1 + NB_BITS + NB_X) {
        const size_t i4 = ((size_t)(b - 1 - NB_BITS) * 256 + t) * 4;
        float4 v = *(const float4*)&x[i4];
        ushort4 o;
        o.x = (unsigned short)f2bf(v.x); o.y = (unsigned short)f2bf(v.y);
        o.z = (unsigned short)f2bf(v.z); o.w = (unsigned short)f2bf(v.w);
        *(ushort4*)&Xbf[i4] = o;
        return;
    }
    if (b < 1 + NB_BITS + NB_X + NB_W) {
        const size_t idx = (size_t)(b - 1 - NB_BITS - NB_X) * 256 + t;   // (h*512+k)*64+d
        const int d = idx & 63;
        const int k = (int)(idx >> 6) & 511;
        const int h = (int)(idx >> 15);
        WF[(((size_t)h * 64 + (k >> 3)) * 64 + d) * 8 + (k & 7)] = f2bf(W[idx]);
        return;
    }
    {
        const size_t idx = (size_t)(b - 1 - NB_BITS - NB_X - NB_W) * 256 + t;  // k*64+d
        const int d = idx & 63;
        const int k = (int)(idx >> 6);
        WoF[(((size_t)(k >> 3)) * 64 + d) * 8 + (k & 7)] = f2bf(Wo[idx]);
    }
}

// ---------------------------------------------------------------- MFMA GEMM [N,512]@[512,64] per head
// bf16 A from global; writes bf16 frag copy of C, fused fs/fd row dot-products,
// and fused per-head stats: gmax(fd) via encoded atomicMax, colmean via atomicAdd.
__global__ void __launch_bounds__(256) k_gemm(
    const short* __restrict__ Xbf, const short* __restrict__ WF,
    const float* __restrict__ av, const float* __restrict__ bv,
    short* __restrict__ WBout, float* __restrict__ fs, float* __restrict__ fd,
    unsigned* __restrict__ gmaxe, float* __restrict__ cm) {
    const int h  = blockIdx.y;
    const int i0 = blockIdx.x * 64;
    const int t = threadIdx.x, w = t >> 6, lane = t & 63;
    const int li = lane & 15, quad = lane >> 4, k0 = quad * 8;
    const int row_a = i0 + w * 16 + li;
    const short* __restrict__ Xr  = Xbf + (size_t)row_a * FDIM;
    const short* __restrict__ WFh = WF + (size_t)h * 64 * D * 8;

    f32x4 c0 = {0.f, 0.f, 0.f, 0.f}, c1 = c0, c2 = c0, c3 = c0;
    #pragma unroll 4
    for (int kt = 0; kt < FDIM; kt += 32) {
        bf16x8 a = *(const bf16x8*)&Xr[kt + k0];
        const short* bb = WFh + (size_t)((kt >> 3) + quad) * (D * 8) + li * 8;
        bf16x8 b0 = *(const bf16x8*)(bb);
        bf16x8 b1 = *(const bf16x8*)(bb + 128);
        bf16x8 b2 = *(const bf16x8*)(bb + 256);
        bf16x8 b3 = *(const bf16x8*)(bb + 384);
        c0 = __builtin_amdgcn_mfma_f32_16x16x32_bf16(a, b0, c0, 0, 0, 0);
        c1 = __builtin_amdgcn_mfma_f32_16x16x32_bf16(a, b1, c1, 0, 0, 0);
        c2 = __builtin_amdgcn_mfma_f32_16x16x32_bf16(a, b2, c2, 0, 0, 0);
        c3 = __builtin_amdgcn_mfma_f32_16x16x32_bf16(a, b3, c3, 0, 0, 0);
    }
    float av4[4], bv4[4];
    #pragma unroll
    for (int t4 = 0; t4 < 4; ++t4) {
        av4[t4] = av[h * D + t4 * 16 + li];
        bv4[t4] = bv[h * D + t4 * 16 + li];
    }
    float tiles[4][4];
    #pragma unroll
    for (int r = 0; r < 4; ++r) { tiles[0][r] = c0[r]; tiles[1][r] = c1[r]; tiles[2][r] = c2[r]; tiles[3][r] = c3[r]; }

    __shared__ float csum[4][64];
    __shared__ float red[4];
    float fdmax = -INFINITY;
    float s4[4] = {0.f, 0.f, 0.f, 0.f};

    #pragma unroll
    for (int r = 0; r < 4; ++r) {
        const int row = i0 + w * 16 + quad * 4 + r;
        float pa = 0.f, pb = 0.f;
        #pragma unroll
        for (int t4 = 0; t4 < 4; ++t4) {
            const float v = tiles[t4][r];
            const int d = t4 * 16 + li;
            WBout[((size_t)h * (N_NODES / 8) + (row >> 3)) * (D * 8) + d * 8 + (row & 7)] = f2bf(v);
            pa += v * av4[t4];
            pb += v * bv4[t4];
            s4[t4] += v;
        }
        #pragma unroll
        for (int off = 1; off < 16; off <<= 1) {
            pa += __shfl_xor(pa, off);
            pb += __shfl_xor(pb, off);
        }
        if (li == 0) {
            fs[(size_t)h * N_NODES + row] = pa;
            fd[(size_t)h * N_NODES + row] = pb;
        }
        fdmax = fmaxf(fdmax, pb);
    }
    fdmax = fmaxf(fdmax, __shfl_xor(fdmax, 16));
    fdmax = fmaxf(fdmax, __shfl_xor(fdmax, 32));
    if (lane == 0) red[w] = fdmax;
    #pragma unroll
    for (int t4 = 0; t4 < 4; ++t4) {
        s4[t4] += __shfl_xor(s4[t4], 16);
        s4[t4] += __shfl_xor(s4[t4], 32);
    }
    if (quad == 0)
        #pragma unroll
        for (int t4 = 0; t4 < 4; ++t4) csum[w][t4 * 16 + li] = s4[t4];
    __syncthreads();
    if (t == 0)
        atomicMax(gmaxe + h, fenc(fmaxf(fmaxf(red[0], red[1]), fmaxf(red[2], red[3]))));
    if (t < 64)
        atomicAdd(&cm[h * D + t],
                  (csum[0][t] + csum[1][t] + csum[2][t] + csum[3][t]) * (1.f / (float)N_NODES));
}

// ---------------------------------------------------------------- MFMA attention aggregation (j-split)
// 256 i-rows/block, 64 rows/wave (4 A-frags per B-frag LDS read). num slabs
// stored bf16. B-tile (16 KB) DMA'd to LDS double-buffered (the staging is the
// traffic compressor: one global read per block, shared by 4 waves — r14's
// barrier-free variant without it thrashed L2 and went 15x over on FETCH).
__global__ void __launch_bounds__(256) k_accum(
    const unsigned int* __restrict__ bits32,
    const short* __restrict__ WB,
    const float* __restrict__ fsb, const float* __restrict__ fdb,
    const unsigned* __restrict__ gmaxe,
    short* __restrict__ num, float* __restrict__ den, int kslab) {

    __shared__ __align__(16) short Bt[2][16 * 64 * 8];   // 2 x 16 KB
    __shared__ __align__(16) float EG[2][256];           // per buf: e[0..127], g[0..127]

    const int h = blockIdx.y, i0 = blockIdx.x * 256, slab = blockIdx.z;
    const int t = threadIdx.x, w = t >> 6, lane = t & 63;
    const int li = lane & 15, quad = lane >> 4, k0 = quad * 8;
    const size_t ho = (size_t)h * N_NODES;
    const float  gm = fdec(gmaxe[h]);
    float Rv[4];
    const unsigned int* __restrict__ brow[4];
    #pragma unroll
    for (int f = 0; f < 4; ++f) {
        const int r = i0 + w * 64 + f * 16 + li;
        Rv[f] = __expf(-0.8f * (fsb[ho + r] + gm));
        brow[f] = bits32 + (size_t)r * (NWORDS * 2);
    }
    const float* __restrict__ fd = fdb + ho;
    const short* __restrict__ Bh = WB + (size_t)h * (N_NODES / 8) * D * 8;

    f32x4 acc[4][4], c5[4];
    #pragma unroll
    for (int f = 0; f < 4; ++f) {
        #pragma unroll
        for (int q = 0; q < 4; ++q) acc[f][q] = (f32x4){0.f, 0.f, 0.f, 0.f};
        c5[f] = (f32x4){0.f, 0.f, 0.f, 0.f};
    }
    bf16x8 ones;
    #pragma unroll
    for (int j = 0; j < 8; ++j) ones[j] = (short)0x3F80;

    const int k_beg = slab * kslab;
    const int ntile = kslab / 128;

    auto stage = [&](int buf, int jt) {
        const short* src = Bh + (size_t)(jt >> 3) * (D * 8);
        #pragma unroll
        for (int p = 0; p < 4; ++p)
            gl2lds16(src + (size_t)(p * 256 + t) * 8, &Bt[buf][(p * 256 + t) * 8]);
        if (w == 0) {
            float2 f2 = *(const float2*)&fd[jt + lane * 2];
            float2 ev, gv;
            ev.x = __expf(f2.x - gm);          ev.y = __expf(f2.y - gm);
            gv.x = __expf(0.2f * (f2.x - gm)); gv.y = __expf(0.2f * (f2.y - gm));
            *(float2*)&EG[buf][lane * 2]       = ev;
            *(float2*)&EG[buf][128 + lane * 2] = gv;
        }
    };

    stage(0, k_beg);
    uint4 bw[4];
    #pragma unroll
    for (int f = 0; f < 4; ++f) bw[f] = *(const uint4*)&brow[f][k_beg >> 5];
    for (int tile = 0; tile < ntile; ++tile) {
        const int jt = k_beg + tile * 128;
        __syncthreads();                                // stage for Bt[tile&1] drained
        if (tile + 1 < ntile) stage((tile + 1) & 1, jt + 128);
        const short* Bl  = Bt[tile & 1];
        const float* EGl = EG[tile & 1];
        unsigned int bwa[4][4];
        #pragma unroll
        for (int f = 0; f < 4; ++f) {
            bwa[f][0] = bw[f].x; bwa[f][1] = bw[f].y; bwa[f][2] = bw[f].z; bwa[f][3] = bw[f].w;
        }
        if (tile + 1 < ntile)
            #pragma unroll
            for (int f = 0; f < 4; ++f) bw[f] = *(const uint4*)&brow[f][(jt + 128) >> 5];
        #pragma unroll
        for (int s = 0; s < 4; ++s) {
            const float4 e0 = *(const float4*)&EGl[s * 32 + k0];
            const float4 e1 = *(const float4*)&EGl[s * 32 + k0 + 4];
            const float4 g0 = *(const float4*)&EGl[128 + s * 32 + k0];
            const float4 g1 = *(const float4*)&EGl[128 + s * 32 + k0 + 4];
            float ev[8], gv[8];
            ev[0] = e0.x; ev[1] = e0.y; ev[2] = e0.z; ev[3] = e0.w;
            ev[4] = e1.x; ev[5] = e1.y; ev[6] = e1.z; ev[7] = e1.w;
            gv[0] = g0.x; gv[1] = g0.y; gv[2] = g0.z; gv[3] = g0.w;
            gv[4] = g1.x; gv[5] = g1.y; gv[6] = g1.z; gv[7] = g1.w;
            const short* bb = Bl + (size_t)((s * 4 + quad) * 64 + li) * 8;
            bf16x8 b0 = *(const bf16x8*)(bb);
            bf16x8 b1 = *(const bf16x8*)(bb + 128);
            bf16x8 b2 = *(const bf16x8*)(bb + 256);
            bf16x8 b3 = *(const bf16x8*)(bb + 384);
            #pragma unroll
            for (int f = 0; f < 4; ++f) {
                const unsigned int byt = (bwa[f][s] >> k0) & 0xFFu;
                unsigned int pa[8];
                #pragma unroll
                for (int j = 0; j < 8; ++j) {
                    const float p = fmaxf(ev[j], gv[j] * Rv[f]);   // == leaky branch select
                    pa[j] = __builtin_bit_cast(unsigned int, p)
                            & (unsigned int)sext_bit(byt, j);
                }
                bf16x8 a;
                unsigned int* au = (unsigned int*)&a;
                au[0] = __builtin_amdgcn_perm(pa[1], pa[0], 0x07060302);
                au[1] = __builtin_amdgcn_perm(pa[3], pa[2], 0x07060302);
                au[2] = __builtin_amdgcn_perm(pa[5], pa[4], 0x07060302);
                au[3] = __builtin_amdgcn_perm(pa[7], pa[6], 0x07060302);
                acc[f][0] = __builtin_amdgcn_mfma_f32_16x16x32_bf16(a, b0, acc[f][0], 0, 0, 0);
                acc[f][1] = __builtin_amdgcn_mfma_f32_16x16x32_bf16(a, b1, acc[f][1], 0, 0, 0);
                acc[f][2] = __builtin_amdgcn_mfma_f32_16x16x32_bf16(a, b2, acc[f][2], 0, 0, 0);
                acc[f][3] = __builtin_amdgcn_mfma_f32_16x16x32_bf16(a, b3, acc[f][3], 0, 0, 0);
                c5[f]     = __builtin_amdgcn_mfma_f32_16x16x32_bf16(a, ones, c5[f], 0, 0, 0);
            }
        }
    }

    const size_t so = (size_t)(slab * gridDim.y + h);
    #pragma unroll
    for (int f = 0; f < 4; ++f) {
        #pragma unroll
        for (int t4 = 0; t4 < 4; ++t4)
            #pragma unroll
            for (int r = 0; r < 4; ++r) {
                const int row = i0 + w * 64 + f * 16 + quad * 4 + r;
                num[(so * N_NODES + row) * D + t4 * 16 + li] = f2bf(acc[f][t4][r]);
            }
        if (li == 0)
            #pragma unroll
            for (int r = 0; r < 4; ++r)
                den[so * N_NODES + i0 + w * 64 + f * 16 + quad * 4 + r] = c5[f][r];
    }
}

// ---------------------------------------------------------------- layer-1 combine (JS=8): norm+fallback+ELU, bf16 out
__global__ void k_post1(const short* __restrict__ num, const float* __restrict__ den,
                        const float* __restrict__ colmean, short* __restrict__ hcat) {
    const int h   = blockIdx.y;
    const int i0  = blockIdx.x * 64;
    const int t   = threadIdx.x;
    const int row = i0 + (t >> 2);
    const int cb  = (t & 3) * 16;
    const size_t HN = (size_t)gridDim.y * N_NODES;
    const size_t r0 = (size_t)h * N_NODES + row;
    float dsum = 0.f;
    #pragma unroll
    for (int s = 0; s < 8; ++s) dsum += den[s * HN + r0];
    const bool  uni  = !(dsum > 0.f);
    const float linv = uni ? 0.f : 1.f / dsum;
    #pragma unroll
    for (int c = 0; c < 4; ++c) {
        const int col = cb + c * 4;
        float4 v = {0.f, 0.f, 0.f, 0.f};
        #pragma unroll
        for (int s = 0; s < 8; ++s) {
            ushort4 a = *(const ushort4*)&num[(s * HN + r0) * D + col];
            v.x += b2f(a.x); v.y += b2f(a.y); v.z += b2f(a.z); v.w += b2f(a.w);
        }
        v.x *= linv; v.y *= linv; v.z *= linv; v.w *= linv;
        if (uni) v = *(const float4*)&colmean[h * D + col];
        v.x = v.x > 0.f ? v.x : __expf(v.x) - 1.f;
        v.y = v.y > 0.f ? v.y : __expf(v.y) - 1.f;
        v.z = v.z > 0.f ? v.z : __expf(v.z) - 1.f;
        v.w = v.w > 0.f ? v.w : __expf(v.w) - 1.f;
        ushort4 o;
        o.x = (unsigned short)f2bf(v.x); o.y = (unsigned short)f2bf(v.y);
        o.z = (unsigned short)f2bf(v.z); o.w = (unsigned short)f2bf(v.w);
        *(ushort4*)&hcat[(size_t)row * (H * D) + h * D + col] = o;
    }
}

// ---------------------------------------------------------------- layer-2 combine (JS=32) + ELU + log_softmax
__global__ void k_lsm(const short* __restrict__ num, const float* __restrict__ den,
                      const float* __restrict__ cm, float* __restrict__ out) {
    const int n    = blockIdx.x * 4 + (threadIdx.x >> 6);
    const int lane = threadIdx.x & 63;
    float v = 0.f, ds = 0.f;
    #pragma unroll
    for (int s = 0; s < 32; ++s)
        v += b2f((unsigned short)num[((size_t)s * N_NODES + n) * D + lane]);
    #pragma unroll
    for (int s = 0; s < 32; ++s) ds += den[(size_t)s * N_NODES + n];
    v = (ds > 0.f) ? v / ds : cm[lane];
    v = v > 0.f ? v : __expf(v) - 1.f;
    float mx = v;
    #pragma unroll
    for (int off = 32; off > 0; off >>= 1) mx = fmaxf(mx, __shfl_xor(mx, off));
    float ex = __expf(v - mx);
    float sum = ex;
    #pragma unroll
    for (int off = 32; off > 0; off >>= 1) sum += __shfl_xor(sum, off);
    out[(size_t)n * D + lane] = (v - mx) - __logf(sum);
}

// ----------------------------------------------------------------
extern "C" void kernel_launch(void* const* d_in, const int* in_sizes, int n_in,
                              void* d_out, int out_size, void* d_ws, size_t ws_size,
                              hipStream_t stream) {
    const float* x      = (const float*)d_in[0];
    const int*   adj    = (const int*)d_in[1];
    const float* W      = (const float*)d_in[2];
    const float* a_src  = (const float*)d_in[3];
    const float* a_dst  = (const float*)d_in[4];
    const float* W_o    = (const float*)d_in[5];
    const float* ao_src = (const float*)d_in[6];
    const float* ao_dst = (const float*)d_in[7];
    float* out = (float*)d_out;

    char* wsp = (char*)d_ws;
    size_t off = 0;
    auto alloc = [&](size_t bytes) -> void* {
        void* p = wsp + off;
        off += (bytes + 255) & ~(size_t)255;
        return p;
    };
    unsigned* adj_bits = (unsigned*)alloc((size_t)N_NODES * NWORDS * 8);
    short*    Xbf   = (short*)alloc((size_t)N_NODES * FDIM * 2);
    short*    WF1   = (short*)alloc((size_t)H * 64 * D * 8 * 2);
    short*    WoF   = (short*)alloc((size_t)64 * D * 8 * 2);
    short*    WhB   = (short*)alloc((size_t)H * N_NODES * D * 2);
    float*    fs1   = (float*)alloc((size_t)H * N_NODES * 4);
    float*    fd1   = (float*)alloc((size_t)H * N_NODES * 4);
    unsigned* gme1  = (unsigned*)alloc((size_t)H * 4);
    float*    cm1   = (float*)alloc((size_t)H * D * 4);
    short*    num1  = (short*)alloc((size_t)8 * H * N_NODES * D * 2);
    float*    den1  = (float*)alloc((size_t)8 * H * N_NODES * 4);
    short*    hcat  = (short*)alloc((size_t)N_NODES * H * D * 2);
    short*    WhoB  = (short*)alloc((size_t)N_NODES * D * 2);
    float*    fs2   = (float*)alloc((size_t)N_NODES * 4);
    float*    fd2   = (float*)alloc((size_t)N_NODES * 4);
    unsigned* gme2  = (unsigned*)alloc(4);
    float*    cm2   = (float*)alloc((size_t)D * 4);
    short*    num2  = (short*)alloc((size_t)32 * N_NODES * D * 2);
    float*    den2  = (float*)alloc((size_t)32 * N_NODES * 4);

    k_pre  <<<dim3(1 + NB_BITS + NB_X + NB_W + NB_WO), dim3(256), 0, stream>>>(
        adj, x, W, W_o, adj_bits, Xbf, WF1, WoF, cm1, cm2, gme1, gme2);

    // layer 1 (8 heads, concat + ELU)
    k_gemm <<<dim3(N_NODES / 64, H), dim3(256), 0, stream>>>(Xbf, WF1, a_src, a_dst,
                                                             WhB, fs1, fd1, gme1, cm1);
    k_accum<<<dim3(N_NODES / 256, H, 8), dim3(256), 0, stream>>>(adj_bits, WhB, fs1, fd1, gme1,
                                                                 num1, den1, N_NODES / 8);
    k_post1<<<dim3(N_NODES / 64, H), dim3(256), 0, stream>>>(num1, den1, cm1, hcat);

    // layer 2 (single output head)
    k_gemm <<<dim3(N_NODES / 64, 1), dim3(256), 0, stream>>>(hcat, WoF, ao_src, ao_dst,
                                                             WhoB, fs2, fd2, gme2, cm2);
    k_accum<<<dim3(N_NODES / 256, 1, 32), dim3(256), 0, stream>>>(adj_bits, WhoB, fs2, fd2, gme2,
                                                                  num2, den2, N_NODES / 32);
    k_lsm  <<<dim3(N_NODES / 4), dim3(256), 0, stream>>>(num2, den2, cm2, out);
}